// Round 8
// baseline (59.033 us; speedup 1.0000x reference)
//
#include <hip/hip_runtime.h>
#include <hip/hip_bf16.h>

// LinearAttention_41798621725051 on MI355X.
// Identity: (qk * v_h) / qk == v_h elementwise (qk strictly positive, finite),
// so reference == cumsum_b( v @ Wv^T ): one bf16 MFMA GEMM (M=16384, N=K=1024),
// batch-cumsum free in the epilogue (C/D frag rows = 4 batch entries of one s).
//
// R8: T3+T4 proper. BK=32, FOUR 32KB LDS buffers (ring), prefetch depth 3,
// counted s_waitcnt vmcnt(8) at tile end (never drain-0 mid-loop; tail peels
// 8->4->0). 2 phases/tile, each {4-8 ds_read + 2 gll + barrier + 16 MFMA +
// barrier} = m201's phase composition. R6/R7's drain-0-per-tile was the
// serializer (m218: counted-vs-drain0 = +38..73%).

typedef short s16x8 __attribute__((ext_vector_type(8)));
typedef float f32x4 __attribute__((ext_vector_type(4)));

constexpr int M_ = 16384, N_ = 1024, K_ = 1024;
constexpr int KT32 = 32;                    // K / 32
constexpr size_t WS_WB   = 33554432;        // Wv bf16 at +32 MB
constexpr size_t WS_NEED = 35651584;        // 34 MB

static __device__ __forceinline__ unsigned cvtpk(float lo, float hi) {
  unsigned r;
  asm("v_cvt_pk_bf16_f32 %0, %1, %2" : "=v"(r) : "v"(lo), "v"(hi));
  return r;
}

// ------------------------- prepass: f32 -> bf16 -------------------------
__global__ __launch_bounds__(256) void cvt_bf16(const float* __restrict__ v,
                                                const float* __restrict__ w,
                                                unsigned short* __restrict__ vb,
                                                unsigned short* __restrict__ wb) {
  const int gs = gridDim.x * blockDim.x;
  const int t0 = blockIdx.x * blockDim.x + threadIdx.x;
  for (int i = t0; i < (M_ * K_ / 4); i += gs) {
    float4 x = ((const float4*)v)[i];
    uint2 p; p.x = cvtpk(x.x, x.y); p.y = cvtpk(x.z, x.w);
    ((uint2*)vb)[i] = p;
  }
  for (int i = t0; i < (N_ * K_ / 4); i += gs) {
    float4 x = ((const float4*)w)[i];
    uint2 p; p.x = cvtpk(x.x, x.y); p.y = cvtpk(x.z, x.w);
    ((uint2*)wb)[i] = p;
  }
}

// ------------------------- main GEMM (bf16 in) --------------------------
#define GLL(srcp, ldsoff)                                                     \
  __builtin_amdgcn_global_load_lds(                                           \
      (__attribute__((address_space(1))) void*)(void*)(srcp),                 \
      (__attribute__((address_space(3))) void*)(void*)(lds + (ldsoff)),       \
      16, 0, 0)

#define SB() __builtin_amdgcn_sched_barrier(0)
#define VMNT(n) asm volatile("s_waitcnt vmcnt(" #n ")" ::: "memory")

#define MFMA_Q(MB, AF, BF)                                                    \
  __builtin_amdgcn_s_setprio(1);                                              \
  _Pragma("unroll") for (int m_ = 0; m_ < 4; ++m_)                            \
  _Pragma("unroll") for (int n_ = 0; n_ < 4; ++n_)                            \
      acc[(MB) + m_][n_] = __builtin_amdgcn_mfma_f32_16x16x32_bf16(           \
          AF[m_], BF[n_], acc[(MB) + m_][n_], 0, 0, 0);                       \
  __builtin_amdgcn_s_setprio(0);

// One K-tile: 2 phases. Reads buf[(KT)&3]; stages tile KT+3 into buf[(KT+3)&3].
#define TILE_BODY(KT, PF, VMWAIT) do {                                        \
    const int ktv_ = (KT);                                                    \
    const char* Rb_ = lds + ((ktv_ & 3) << 15);                               \
    const int sb_ = (((ktv_ + 3) & 3) << 15);                                 \
    const int ko_ = (ktv_ + 3) * 64;                                          \
    s16x8 bf[4], af[4], ag[4];                                                \
    /* P0: B frags + A-lo frags; stage A of kt+3 */                           \
    _Pragma("unroll") for (int n_ = 0; n_ < 4; ++n_)                          \
      bf[n_] = *(const s16x8*)(Rb_ + RB + n_ * 1024);                         \
    _Pragma("unroll") for (int m_ = 0; m_ < 4; ++m_)                          \
      af[m_] = *(const s16x8*)(Rb_ + RA + m_ * 1024);                         \
    if (PF) { GLL(srcA0 + ko_, sb_ + ldsA0); GLL(srcA1 + ko_, sb_ + ldsA1); } \
    SB();                                                                     \
    __builtin_amdgcn_s_barrier();                                             \
    MFMA_Q(0, af, bf);                                                        \
    __builtin_amdgcn_s_barrier();                                             \
    /* P1: A-hi frags; stage B of kt+3; counted vmcnt before closing bar */   \
    _Pragma("unroll") for (int m_ = 0; m_ < 4; ++m_)                          \
      ag[m_] = *(const s16x8*)(Rb_ + RA + (4 + m_) * 1024);                   \
    if (PF) { GLL(srcB0 + ko_, sb_ + ldsB0); GLL(srcB1 + ko_, sb_ + ldsB1); } \
    SB();                                                                     \
    __builtin_amdgcn_s_barrier();                                             \
    MFMA_Q(4, ag, bf);                                                        \
    VMWAIT;                                                                   \
    __builtin_amdgcn_s_barrier();                                             \
  } while (0)

__global__ __launch_bounds__(512, 2) void la_gemm8(
    const unsigned short* __restrict__ Ab,   // (M,K) bf16
    const unsigned short* __restrict__ Bb,   // (N,K) bf16
    float* __restrict__ out) {
  extern __shared__ char lds[];   // 4 bufs x [A 16K | B 16K]

  const int tid = threadIdx.x, lane = tid & 63, wave = tid >> 6;
  const int wr = wave >> 2, wc = wave & 3;

  // XCD-affine: 4 nt-blocks of one mt share an XCD's L2.
  const int gid = blockIdx.x;
  const int xcd = gid & 7, qq = gid >> 3;
  const int mt = xcd * 8 + (qq >> 2), nt = qq & 3;

  // ---- fragment read bases. Swizzle: chunk' = chunk ^ ((row>>1)&3);
  // row = (16-mult) + (lane&15)  =>  s = ((lane&15)>>1)&3.
  const int l15 = lane & 15;
  const int lswz = (((lane >> 4) ^ ((l15 >> 1) & 3)) << 4);
  const int RA = (wr * 128 + l15) * 64 + lswz;            // A at buf+0
  const int RB = 16384 + (wc * 64 + l15) * 64 + lswz;     // B at buf+16K

  // ---- staging: per-lane pre-swizzled global source (involution match).
  // gll unit = 16 rows x 64B (1 KB). lane l: row = u*16 + (l>>2),
  // src chunk = (l&3) ^ ((l>>3)&3)   [since (row>>1)&3 = (l>>3)&3].
  const int cg = ((lane & 3) ^ ((lane >> 3) & 3)) << 4;
  const int u0 = 2 * wave, u1 = 2 * wave + 1;
  const char* srcA0 = (const char*)Ab + (size_t)(mt * 256 + u0 * 16 + (lane >> 2)) * 2048 + cg;
  const char* srcA1 = (const char*)Ab + (size_t)(mt * 256 + u1 * 16 + (lane >> 2)) * 2048 + cg;
  const char* srcB0 = (const char*)Bb + (size_t)(nt * 256 + u0 * 16 + (lane >> 2)) * 2048 + cg;
  const char* srcB1 = (const char*)Bb + (size_t)(nt * 256 + u1 * 16 + (lane >> 2)) * 2048 + cg;
  const int ldsA0 = u0 * 1024, ldsA1 = u1 * 1024;
  const int ldsB0 = 16384 + u0 * 1024, ldsB1 = 16384 + u1 * 1024;

  f32x4 acc[8][4] = {};

  // ---- prologue: stage tiles 0,1,2 into bufs 0,1,2 (12 gll/wave in flight)
#pragma unroll
  for (int t = 0; t < 3; ++t) {
    const int sb = t << 15, ko = t * 64;
    GLL(srcA0 + ko, sb + ldsA0); GLL(srcA1 + ko, sb + ldsA1);
    GLL(srcB0 + ko, sb + ldsB0); GLL(srcB1 + ko, sb + ldsB1);
  }
  VMNT(8);              // tile 0 landed (oldest 4 retired)
  __syncthreads();

  // ---- main loop: counted vmcnt(8) steady-state; tail peels 4 -> 0.
  for (int kt = 0; kt < 29; ++kt) TILE_BODY(kt, true, VMNT(8));
  TILE_BODY(29, false, VMNT(4));
  TILE_BODY(30, false, VMNT(0));
  TILE_BODY(31, false, (void)0);

  // ---- epilogue: batch-cumsum = prefix over f32x4 (rows s*4 + 0..3)
#pragma unroll
  for (int m = 0; m < 8; ++m) {
    const int row0 = mt * 256 + wr * 128 + m * 16 + ((lane >> 4) << 2);
#pragma unroll
    for (int n = 0; n < 4; ++n) {
      f32x4 a = acc[m][n];
      a.y += a.x;  a.z += a.y;  a.w += a.z;
      const int col = nt * 256 + wc * 64 + n * 16 + l15;
      out[(size_t)(row0 + 0) * N_ + col] = a.x;
      out[(size_t)(row0 + 1) * N_ + col] = a.y;
      out[(size_t)(row0 + 2) * N_ + col] = a.z;
      out[(size_t)(row0 + 3) * N_ + col] = a.w;
    }
  }
}

// ------------------- fallback: R3 fused kernel (proven) -------------------
__global__ __launch_bounds__(512, 2) void la_gemm_fb(
    const float* __restrict__ Vp, const float* __restrict__ Wp, float* __restrict__ out) {
  extern __shared__ char lds[];
  const int tid = threadIdx.x, lane = tid & 63, wave = tid >> 6;
  const int wr = wave >> 2, wc = wave & 3;
  const int gid = blockIdx.x, xcd = gid & 7, q = gid >> 3;
  const int mt = xcd * 8 + (q >> 2), nt = q & 3;
  const int srow = tid >> 3, schunk = tid & 7;
  const float* sAp = Vp + (size_t)(mt * 256 + srow) * K_ + schunk * 8;
  const float* sBp = Wp + (size_t)(nt * 256 + srow) * K_ + schunk * 8;
  const int wbyte = srow * 128 + ((schunk ^ (srow & 7)) << 4);
  const int basa0 = (wr * 128 + (lane & 15)) * 128 + (((lane >> 4) ^ (lane & 7)) << 4);
  const int basb0 = (wc * 64 + (lane & 15)) * 128 + (((lane >> 4) ^ (lane & 7)) << 4);
  f32x4 acc[8][4] = {};
  float4 sa[8], sb[8];
  auto loadset = [&](int kt) {
#pragma unroll
    for (int i = 0; i < 4; ++i) {
      const float* pa = sAp + kt * 64 + i * (64 * K_);
      const float* pb = sBp + kt * 64 + i * (64 * K_);
      sa[2*i] = *(const float4*)pa; sa[2*i+1] = *(const float4*)(pa + 4);
      sb[2*i] = *(const float4*)pb; sb[2*i+1] = *(const float4*)(pb + 4);
    }
  };
  auto cvtwrite = [&](int buf) {
    char* A = lds + buf * 65536; char* B = A + 32768;
#pragma unroll
    for (int i = 0; i < 4; ++i) {
      uint4 wa, wb;
      wa.x = cvtpk(sa[2*i].x, sa[2*i].y);     wa.y = cvtpk(sa[2*i].z, sa[2*i].w);
      wa.z = cvtpk(sa[2*i+1].x, sa[2*i+1].y); wa.w = cvtpk(sa[2*i+1].z, sa[2*i+1].w);
      wb.x = cvtpk(sb[2*i].x, sb[2*i].y);     wb.y = cvtpk(sb[2*i].z, sb[2*i].w);
      wb.z = cvtpk(sb[2*i+1].x, sb[2*i+1].y); wb.w = cvtpk(sb[2*i+1].z, sb[2*i+1].w);
      *(uint4*)(A + wbyte + i * 8192) = wa;
      *(uint4*)(B + wbyte + i * 8192) = wb;
    }
  };
  auto compute = [&](int buf) {
    const char* A = lds + buf * 65536; const char* B = A + 32768;
#pragma unroll
    for (int kk = 0; kk < 2; ++kk) {
      const int ba = basa0 ^ (kk ? 64 : 0), bb = basb0 ^ (kk ? 64 : 0);
      s16x8 bf[4];
#pragma unroll
      for (int n = 0; n < 4; ++n) bf[n] = *(const s16x8*)(B + bb + n * 2048);
#pragma unroll
      for (int mh = 0; mh < 2; ++mh) {
        s16x8 af[4];
#pragma unroll
        for (int m = 0; m < 4; ++m) af[m] = *(const s16x8*)(A + ba + (mh * 4 + m) * 2048);
        __builtin_amdgcn_s_setprio(1);
#pragma unroll
        for (int m = 0; m < 4; ++m)
#pragma unroll
          for (int n = 0; n < 4; ++n)
            acc[mh*4+m][n] = __builtin_amdgcn_mfma_f32_16x16x32_bf16(af[m], bf[n], acc[mh*4+m][n], 0, 0, 0);
        __builtin_amdgcn_s_setprio(0);
      }
    }
  };
  loadset(0); cvtwrite(0); __syncthreads();
  for (int kt = 0; kt < 16; ++kt) {
    const int cur = kt & 1;
    if (kt + 1 < 16) loadset(kt + 1);
    compute(cur);
    if (kt + 1 < 16) cvtwrite(cur ^ 1);
    __syncthreads();
  }
#pragma unroll
  for (int m = 0; m < 8; ++m) {
    const int row0 = mt * 256 + wr * 128 + m * 16 + ((lane >> 4) << 2);
#pragma unroll
    for (int n = 0; n < 4; ++n) {
      f32x4 a = acc[m][n];
      a.y += a.x; a.z += a.y; a.w += a.z;
      const int col = nt * 256 + wc * 64 + n * 16 + (lane & 15);
      out[(size_t)(row0 + 0) * N_ + col] = a.x;
      out[(size_t)(row0 + 1) * N_ + col] = a.y;
      out[(size_t)(row0 + 2) * N_ + col] = a.z;
      out[(size_t)(row0 + 3) * N_ + col] = a.w;
    }
  }
}

extern "C" void kernel_launch(void* const* d_in, const int* in_sizes, int n_in,
                              void* d_out, int out_size, void* d_ws, size_t ws_size,
                              hipStream_t stream) {
  // setup_inputs order: q, k, v, Wq, Wk, Wv — only v and Wv matter.
  const float* v  = (const float*)d_in[2];
  const float* Wv = (const float*)d_in[5];
  float* out = (float*)d_out;
  (void)in_sizes; (void)n_in; (void)out_size;

  if (ws_size >= WS_NEED) {
    unsigned short* vb = (unsigned short*)d_ws;
    unsigned short* wb = (unsigned short*)((char*)d_ws + WS_WB);
    cvt_bf16<<<dim3(2048), dim3(256), 0, stream>>>(v, Wv, vb, wb);
    hipFuncSetAttribute((const void*)la_gemm8,
                        hipFuncAttributeMaxDynamicSharedMemorySize, 131072);
    la_gemm8<<<dim3(256), dim3(512), 131072, stream>>>(vb, wb, out);
  } else {
    hipFuncSetAttribute((const void*)la_gemm_fb,
                        hipFuncAttributeMaxDynamicSharedMemorySize, 131072);
    la_gemm_fb<<<dim3(256), dim3(512), 131072, stream>>>(v, Wv, out);
  }
}